// Round 5
// baseline (543.471 us; speedup 1.0000x reference)
//
#include <hip/hip_runtime.h>
#include <hip/hip_bf16.h>
#include <stdint.h>

#define DIN 4096
#define DOUT 4096
#define BK 64
#define NT (DIN / BK)   // 64 K-tiles

typedef __attribute__((ext_vector_type(8))) short short8;
typedef __attribute__((ext_vector_type(8))) unsigned short ushort8;
typedef __attribute__((ext_vector_type(4))) float f32x4;

__device__ inline unsigned short f2bf(float f) {
    union { float f; unsigned u; } v; v.f = f;
    unsigned r = v.u + 0x7fffu + ((v.u >> 16) & 1u);   // RNE
    return (unsigned short)(r >> 16);
}

// ---- prep 1: x (f32) -> bf16, 8 elems/thread --------------------------------
__global__ void cvt_x_kernel(const float* __restrict__ x, ushort* __restrict__ xb, long n8) {
    long i = (long)blockIdx.x * blockDim.x + threadIdx.x;
    if (i >= n8) return;
    const float4* p = (const float4*)(x + i * 8);
    float4 v0 = p[0], v1 = p[1];
    ushort8 o;
    o[0] = f2bf(v0.x); o[1] = f2bf(v0.y); o[2] = f2bf(v0.z); o[3] = f2bf(v0.w);
    o[4] = f2bf(v1.x); o[5] = f2bf(v1.y); o[6] = f2bf(v1.z); o[7] = f2bf(v1.w);
    *(ushort8*)(xb + i * 8) = o;
}

// ---- prep 2: Wt[e][d] = bf16(base[d][e] + c*mask[d][e])  (64x64 LDS transpose)
__global__ void make_wt_kernel(const float* __restrict__ base, const int* __restrict__ mask,
                               const float* __restrict__ coeff, ushort* __restrict__ wt) {
    __shared__ float tile[64][65];
    const float c = coeff[0];
    const int t = threadIdx.x;                 // 256 threads
    const int bd = blockIdx.x >> 6;            // d-tile
    const int be = blockIdx.x & 63;            // e-tile
    const int d0 = bd * 64, e0 = be * 64;
#pragma unroll
    for (int i = 0; i < 4; ++i) {
        int idx = i * 256 + t;                 // 0..1023 float4-index
        int r = idx >> 4;                      // d-row 0..63
        int c4 = (idx & 15) << 2;              // e-col
        const float4 bv = *(const float4*)(base + (size_t)(d0 + r) * DOUT + e0 + c4);
        const int4  mv = *(const int4*)(mask + (size_t)(d0 + r) * DOUT + e0 + c4);
        tile[r][c4 + 0] = bv.x + c * (float)mv.x;
        tile[r][c4 + 1] = bv.y + c * (float)mv.y;
        tile[r][c4 + 2] = bv.z + c * (float)mv.z;
        tile[r][c4 + 3] = bv.w + c * (float)mv.w;
    }
    __syncthreads();
#pragma unroll
    for (int i = 0; i < 8; ++i) {
        int idx = i * 256 + t;                 // 0..2047 pair index
        int r = idx >> 5;                      // e-row 0..63
        int p = (idx & 31) << 1;               // d-col pair
        ushort2 o;
        o.x = f2bf(tile[p][r]);
        o.y = f2bf(tile[p + 1][r]);
        *(ushort2*)(wt + (size_t)(e0 + r) * DIN + d0 + p) = o;
    }
}

// ---- GEMM: 256x256, BK=64, 8-phase + one-phase-ahead register pipeline ------
// Fragments for phase p+1 are ds_read-issued during phase p; waits are counted
// lgkmcnt so the LDS drain overlaps the MFMA cluster (m201/m218 T4 for lgkm).
// vmcnt staging protocol identical to verified rounds 2/4 (+2 early vmcnt(6)).

#define MFMA(d, va, vb) d = __builtin_amdgcn_mfma_f32_16x16x32_bf16(va, vb, d, 0, 0, 0)

#define MFMA16(AOFF, x0,x1,x2,x3, y0,y1,y2,y3) \
    MFMA(acc[AOFF+0][0],x0,y0); MFMA(acc[AOFF+0][1],x0,y1); MFMA(acc[AOFF+0][2],x0,y2); MFMA(acc[AOFF+0][3],x0,y3); \
    MFMA(acc[AOFF+1][0],x1,y0); MFMA(acc[AOFF+1][1],x1,y1); MFMA(acc[AOFF+1][2],x1,y2); MFMA(acc[AOFF+1][3],x1,y3); \
    MFMA(acc[AOFF+2][0],x2,y0); MFMA(acc[AOFF+2][1],x2,y1); MFMA(acc[AOFF+2][2],x2,y2); MFMA(acc[AOFF+2][3],x2,y3); \
    MFMA(acc[AOFF+3][0],x3,y0); MFMA(acc[AOFF+3][1],x3,y1); MFMA(acc[AOFF+3][2],x3,y2); MFMA(acc[AOFF+3][3],x3,y3);

#define GLL(P, L) \
    __builtin_amdgcn_global_load_lds( \
        (const __attribute__((address_space(1))) void*)(P), \
        (__attribute__((address_space(3))) void*)(L), 16, 0, 0)

#define RDA(BUF,KK,OH,MM) (*(const short8*)&lA[BUF][KK][aoff + (OH)*2048 + (MM)*512])
#define RDB(BUF,KK,NN)    (*(const short8*)&lB[BUF][KK][boff + (NN)*512])

#define STAGE_A(BUF,KK,OFE) { GLL(gA0 + (OFE), &lA[BUF][KK][doff]); \
                              GLL(gA1 + (OFE), &lA[BUF][KK][doff + 4096]); }
#define STAGE_B(BUF,KK,OFE) { GLL(gB0 + (OFE), &lB[BUF][KK][doff]); \
                              GLL(gB1 + (OFE), &lB[BUF][KK][doff + 4096]); }

#define WAITL(N)  asm volatile("s_waitcnt lgkmcnt(" #N ")" ::: "memory")
#define WAITV(N)  asm volatile("s_waitcnt vmcnt(" #N ")" ::: "memory")
#define SCHEDB    __builtin_amdgcn_sched_barrier(0)
#define SBAR      __builtin_amdgcn_s_barrier()

// Per-wave DS FIFO audit (steady state), 4 reads per aX set, 8 per (aX+bX):
//  ph1 wait lgkm(4):  out={aP,bP}(8)+aQ(4) -> drains aP,bP   (MFMA aP*bP)
//  ph2 wait lgkm(8):  out=aQ(4)+{aP,bQ}(8) -> drains aQ      (MFMA aQ*bP)
//  ph3 wait lgkm(4):  out={aP,bQ}(8)+aQ(4) -> drains aP,bQ   (MFMA aP*bQ)
//  ph4 wait lgkm(8):  out=aQ(4)+{aP',bP'}(8) -> drains aQ    (MFMA aQ*bQ)
// ph4 vmcnt(6): 4 oldest GLL = prev tile ph3/4 = (BUF^1).kk0 -> safe to read.
#define KTILE(BUF, G1, G2, NEXT, OFE1, OFE2) \
  { \
    /* ---- ph1: MFMA kk0/oh0 ---- */ \
    aQ0=RDA(BUF,0,1,0); aQ1=RDA(BUF,0,1,1); aQ2=RDA(BUF,0,1,2); aQ3=RDA(BUF,0,1,3); \
    if (G1) STAGE_A(1-(BUF), 1, OFE1) \
    SCHEDB; SBAR; \
    WAITL(4); SCHEDB; \
    __builtin_amdgcn_s_setprio(1); \
    MFMA16(0, aP0,aP1,aP2,aP3, bP0,bP1,bP2,bP3) \
    __builtin_amdgcn_s_setprio(0); \
    SCHEDB; SBAR; \
    /* ---- ph2: MFMA kk0/oh1 ---- */ \
    WAITV(6); \
    aP0=RDA(BUF,1,0,0); aP1=RDA(BUF,1,0,1); aP2=RDA(BUF,1,0,2); aP3=RDA(BUF,1,0,3); \
    bQ0=RDB(BUF,1,0); bQ1=RDB(BUF,1,1); bQ2=RDB(BUF,1,2); bQ3=RDB(BUF,1,3); \
    if (G1) STAGE_B(1-(BUF), 1, OFE1) \
    SCHEDB; SBAR; \
    WAITL(8); SCHEDB; \
    __builtin_amdgcn_s_setprio(1); \
    MFMA16(4, aQ0,aQ1,aQ2,aQ3, bP0,bP1,bP2,bP3) \
    __builtin_amdgcn_s_setprio(0); \
    SCHEDB; SBAR; \
    /* ---- ph3: MFMA kk1/oh0 ---- */ \
    aQ0=RDA(BUF,1,1,0); aQ1=RDA(BUF,1,1,1); aQ2=RDA(BUF,1,1,2); aQ3=RDA(BUF,1,1,3); \
    if (G2) STAGE_A(BUF, 0, OFE2) \
    SCHEDB; SBAR; \
    WAITL(4); SCHEDB; \
    __builtin_amdgcn_s_setprio(1); \
    MFMA16(0, aP0,aP1,aP2,aP3, bQ0,bQ1,bQ2,bQ3) \
    __builtin_amdgcn_s_setprio(0); \
    SCHEDB; SBAR; \
    /* ---- ph4: MFMA kk1/oh1; pre-read next tile kk0 from other buf ---- */ \
    WAITV(6); \
    aP0=RDA(1-(BUF),0,0,0); aP1=RDA(1-(BUF),0,0,1); aP2=RDA(1-(BUF),0,0,2); aP3=RDA(1-(BUF),0,0,3); \
    bP0=RDB(1-(BUF),0,0); bP1=RDB(1-(BUF),0,1); bP2=RDB(1-(BUF),0,2); bP3=RDB(1-(BUF),0,3); \
    if (G2) STAGE_B(BUF, 0, OFE2) \
    SCHEDB; SBAR; \
    WAITL(8); SCHEDB; \
    __builtin_amdgcn_s_setprio(1); \
    MFMA16(4, aQ0,aQ1,aQ2,aQ3, bQ0,bQ1,bQ2,bQ3) \
    __builtin_amdgcn_s_setprio(0); \
    if (G2)        { WAITV(4); } \
    else if (NEXT) { WAITV(0); } \
    SCHEDB; SBAR; SCHEDB; \
  }

__global__ __launch_bounds__(512, 2) void gemm_kernel(const ushort* __restrict__ A,
                                                      const ushort* __restrict__ Bt,
                                                      float* __restrict__ C) {
    __shared__ __align__(16) ushort lA[2][2][256 * 32];
    __shared__ __align__(16) ushort lB[2][2][256 * 32];

    const int tid = threadIdx.x;
    const int lane = tid & 63;
    const int wave = tid >> 6;

    const int nbn = DOUT / 256;               // 16
    const int nwg = gridDim.x;                // 512 (multiple of 8)
    int bid = blockIdx.x;
    int cpx = nwg >> 3;
    int s = (bid & 7) * cpx + (bid >> 3);     // XCD-contiguous chunks
    const int m0 = (s / nbn) * 256;
    const int n0 = (s % nbn) * 256;

    const int wr = wave >> 2;                 // 0..1  (M half)
    const int wc = wave & 3;                  // 0..3  (N quarter)
    const int fr = lane & 15;
    const int fq = lane >> 4;                 // 0..3

    const int st_r = tid >> 2;                // 0..127

    // per-thread constant offsets (ushort elems); read swizzle elem-xor ((fr>>1)&3)<<3
    const int sx = ((fr >> 1) & 3) << 3;
    const int aoff = (wr * 128 + fr) * 32 + ((fq << 3) ^ sx);
    const int boff = (wc * 64 + fr) * 32 + ((fq << 3) ^ sx);
    const int doff = tid * 8;                 // linear stage dest
    const int sce = ((tid & 3) << 3) ^ (((st_r >> 1) & 3) << 3);   // inv-swz source
    const ushort* gA0 = A  + (size_t)(m0 + st_r) * DIN + sce;
    const ushort* gA1 = gA0 + (size_t)128 * DIN;
    const ushort* gB0 = Bt + (size_t)(n0 + st_r) * DIN + sce;
    const ushort* gB1 = gB0 + (size_t)128 * DIN;

    f32x4 acc[8][4] = {};
    short8 aP0, aP1, aP2, aP3, aQ0, aQ1, aQ2, aQ3;
    short8 bP0, bP1, bP2, bP3, bQ0, bQ1, bQ2, bQ3;

    // prologue: tile0 both halves + tile1.kk0 staged (12 GLL/wave)
    STAGE_A(0, 0, 0)   STAGE_B(0, 0, 0)
    STAGE_A(0, 1, 32)  STAGE_B(0, 1, 32)
    STAGE_A(1, 0, 64)  STAGE_B(1, 0, 64)
    WAITV(8);                                  // tile0.kk0 (oldest 4) landed
    SBAR;
    // preload ph1 frags for tile0
    aP0=RDA(0,0,0,0); aP1=RDA(0,0,0,1); aP2=RDA(0,0,0,2); aP3=RDA(0,0,0,3);
    bP0=RDB(0,0,0);   bP1=RDB(0,0,1);   bP2=RDB(0,0,2);   bP3=RDB(0,0,3);
    SCHEDB;

    for (int u = 0; u < NT; u += 2) {
        KTILE(0, 1, (u + 2 < NT), 1, 96, 128)
        KTILE(1, (u + 2 < NT), (u + 3 < NT), (u + 2 < NT), 160, 192)
        gA0 += 128; gA1 += 128; gB0 += 128; gB1 += 128;
    }

    // epilogue: C/D frag layout col=fr, row=fq*4+j
#pragma unroll
    for (int a = 0; a < 8; ++a) {
        int grow = m0 + wr * 128 + (a >> 2) * 64 + (a & 3) * 16 + fq * 4;
#pragma unroll
        for (int n = 0; n < 4; ++n) {
            int gcol = n0 + wc * 64 + n * 16 + fr;
#pragma unroll
            for (int j = 0; j < 4; ++j)
                C[(size_t)(grow + j) * DOUT + gcol] = acc[a][n][j];
        }
    }
}

extern "C" void kernel_launch(void* const* d_in, const int* in_sizes, int n_in,
                              void* d_out, int out_size, void* d_ws, size_t ws_size,
                              hipStream_t stream) {
    const float* x = (const float*)d_in[0];
    const float* base = (const float*)d_in[1];
    const float* coeff = (const float*)d_in[2];
    const int* mask = (const int*)d_in[3];
    float* out = (float*)d_out;

    const int M = in_sizes[0] / DIN;           // 8192
    ushort* xb = (ushort*)d_ws;                // M*DIN bf16  (64 MB)
    ushort* wt = xb + (size_t)M * DIN;         // DOUT*DIN bf16 (32 MB)

    long n8 = (long)M * DIN / 8;
    cvt_x_kernel<<<(int)((n8 + 255) / 256), 256, 0, stream>>>(x, xb, n8);
    make_wt_kernel<<<(DIN / 64) * (DOUT / 64), 256, 0, stream>>>(base, mask, coeff, wt);

    const int nwg = (M / 256) * (DOUT / 256);  // 512
    gemm_kernel<<<nwg, 512, 0, stream>>>(xb, wt, out);
}

// Round 6
// 335.339 us; speedup vs baseline: 1.6207x; 1.6207x over previous
//
#include <hip/hip_runtime.h>
#include <hip/hip_bf16.h>
#include <stdint.h>

#define DIN 4096
#define DOUT 4096
#define BK 64
#define NT (DIN / BK)   // 64 K-tiles

typedef __attribute__((ext_vector_type(8))) short short8;
typedef __attribute__((ext_vector_type(8))) unsigned short ushort8;
typedef __attribute__((ext_vector_type(4))) float f32x4;

__device__ inline unsigned short f2bf(float f) {
    union { float f; unsigned u; } v; v.f = f;
    unsigned r = v.u + 0x7fffu + ((v.u >> 16) & 1u);   // RNE
    return (unsigned short)(r >> 16);
}

// ---- prep 1: x (f32) -> bf16, 8 elems/thread --------------------------------
__global__ void cvt_x_kernel(const float* __restrict__ x, ushort* __restrict__ xb, long n8) {
    long i = (long)blockIdx.x * blockDim.x + threadIdx.x;
    if (i >= n8) return;
    const float4* p = (const float4*)(x + i * 8);
    float4 v0 = p[0], v1 = p[1];
    ushort8 o;
    o[0] = f2bf(v0.x); o[1] = f2bf(v0.y); o[2] = f2bf(v0.z); o[3] = f2bf(v0.w);
    o[4] = f2bf(v1.x); o[5] = f2bf(v1.y); o[6] = f2bf(v1.z); o[7] = f2bf(v1.w);
    *(ushort8*)(xb + i * 8) = o;
}

// ---- prep 2: Wt[e][d] = bf16(base[d][e] + c*mask[d][e])  (64x64 LDS transpose)
__global__ void make_wt_kernel(const float* __restrict__ base, const int* __restrict__ mask,
                               const float* __restrict__ coeff, ushort* __restrict__ wt) {
    __shared__ float tile[64][65];
    const float c = coeff[0];
    const int t = threadIdx.x;                 // 256 threads
    const int bd = blockIdx.x >> 6;            // d-tile
    const int be = blockIdx.x & 63;            // e-tile
    const int d0 = bd * 64, e0 = be * 64;
#pragma unroll
    for (int i = 0; i < 4; ++i) {
        int idx = i * 256 + t;                 // 0..1023 float4-index
        int r = idx >> 4;                      // d-row 0..63
        int c4 = (idx & 15) << 2;              // e-col
        const float4 bv = *(const float4*)(base + (size_t)(d0 + r) * DOUT + e0 + c4);
        const int4  mv = *(const int4*)(mask + (size_t)(d0 + r) * DOUT + e0 + c4);
        tile[r][c4 + 0] = bv.x + c * (float)mv.x;
        tile[r][c4 + 1] = bv.y + c * (float)mv.y;
        tile[r][c4 + 2] = bv.z + c * (float)mv.z;
        tile[r][c4 + 3] = bv.w + c * (float)mv.w;
    }
    __syncthreads();
#pragma unroll
    for (int i = 0; i < 8; ++i) {
        int idx = i * 256 + t;                 // 0..2047 pair index
        int r = idx >> 5;                      // e-row 0..63
        int p = (idx & 31) << 1;               // d-col pair
        ushort2 o;
        o.x = f2bf(tile[p][r]);
        o.y = f2bf(tile[p + 1][r]);
        *(ushort2*)(wt + (size_t)(e0 + r) * DIN + d0 + p) = o;
    }
}

// ---- GEMM: 256x256 tile, BK=64, 8-phase schedule (T2+T3+T4+T5) --------------
// Schedule byte-identical to verified round 4. Round-6 change: n-major
// block->XCD mapping so each XCD's 32 concurrent blocks share ONE B-panel
// (2 MB, L2-resident) -> beyond-L2 staged volume ~2.05 GB -> ~1.1 GB.

#define MFMA(d, va, vb) d = __builtin_amdgcn_mfma_f32_16x16x32_bf16(va, vb, d, 0, 0, 0)

#define GLL(P, L) \
    __builtin_amdgcn_global_load_lds( \
        (const __attribute__((address_space(1))) void*)(P), \
        (__attribute__((address_space(3))) void*)(L), 16, 0, 0)

// element offsets: kk stride 32, K-tile stride 64, row stride 32 (per [buf][kk] region)
#define RDA(BUF,KK,OH,MM) (*(const short8*)&lA[BUF][KK][aoff + (OH)*2048 + (MM)*512])
#define RDB(BUF,KK,NN)    (*(const short8*)&lB[BUF][KK][boff + (NN)*512])

#define STAGE_A(BUF,KK,OFE) { GLL(gA0 + (OFE), &lA[BUF][KK][doff]); \
                              GLL(gA1 + (OFE), &lA[BUF][KK][doff + 4096]); }
#define STAGE_B(BUF,KK,OFE) { GLL(gB0 + (OFE), &lB[BUF][KK][doff]); \
                              GLL(gB1 + (OFE), &lB[BUF][KK][doff + 4096]); }

#define PHASE_CORE(AOFF) \
    __builtin_amdgcn_s_barrier(); \
    asm volatile("s_waitcnt lgkmcnt(0)" ::: "memory"); \
    __builtin_amdgcn_sched_barrier(0); \
    __builtin_amdgcn_s_setprio(1); \
    MFMA(acc[AOFF+0][0],a0,b0); MFMA(acc[AOFF+0][1],a0,b1); MFMA(acc[AOFF+0][2],a0,b2); MFMA(acc[AOFF+0][3],a0,b3); \
    MFMA(acc[AOFF+1][0],a1,b0); MFMA(acc[AOFF+1][1],a1,b1); MFMA(acc[AOFF+1][2],a1,b2); MFMA(acc[AOFF+1][3],a1,b3); \
    MFMA(acc[AOFF+2][0],a2,b0); MFMA(acc[AOFF+2][1],a2,b1); MFMA(acc[AOFF+2][2],a2,b2); MFMA(acc[AOFF+2][3],a2,b3); \
    MFMA(acc[AOFF+3][0],a3,b0); MFMA(acc[AOFF+3][1],a3,b1); MFMA(acc[AOFF+3][2],a3,b2); MFMA(acc[AOFF+3][3],a3,b3); \
    __builtin_amdgcn_s_setprio(0);

// K-tile: 4 phases; stage schedule (verified round 2/4):
//  ph1: stage A.kk1(U+1)->other buf   ph2: stage B.kk1(U+1)
//  ph3: stage A.kk0(U+2)->this buf    ph4: stage B.kk0(U+2)
// boundary: vmcnt(4) steady; vmcnt(0) at tail.  OFE in ushort elements
// relative to the iteration base (pointers advance 128/iter).
#define KTILE(BUF, G1, G2, NEXT, OFE1, OFE2) \
  { \
    short8 a0,a1,a2,a3,b0,b1,b2,b3; \
    a0=RDA(BUF,0,0,0); a1=RDA(BUF,0,0,1); a2=RDA(BUF,0,0,2); a3=RDA(BUF,0,0,3); \
    b0=RDB(BUF,0,0); b1=RDB(BUF,0,1); b2=RDB(BUF,0,2); b3=RDB(BUF,0,3); \
    if (G1) STAGE_A(1-(BUF), 1, OFE1) \
    PHASE_CORE(0) \
    __builtin_amdgcn_s_barrier(); \
    a0=RDA(BUF,0,1,0); a1=RDA(BUF,0,1,1); a2=RDA(BUF,0,1,2); a3=RDA(BUF,0,1,3); \
    if (G1) STAGE_B(1-(BUF), 1, OFE1) \
    PHASE_CORE(4) \
    __builtin_amdgcn_s_barrier(); \
    a0=RDA(BUF,1,0,0); a1=RDA(BUF,1,0,1); a2=RDA(BUF,1,0,2); a3=RDA(BUF,1,0,3); \
    b0=RDB(BUF,1,0); b1=RDB(BUF,1,1); b2=RDB(BUF,1,2); b3=RDB(BUF,1,3); \
    if (G2) STAGE_A(BUF, 0, OFE2) \
    PHASE_CORE(0) \
    __builtin_amdgcn_s_barrier(); \
    a0=RDA(BUF,1,1,0); a1=RDA(BUF,1,1,1); a2=RDA(BUF,1,1,2); a3=RDA(BUF,1,1,3); \
    if (G2) STAGE_B(BUF, 0, OFE2) \
    PHASE_CORE(4) \
    if (G2)        { asm volatile("s_waitcnt vmcnt(4)" ::: "memory"); } \
    else if (NEXT) { asm volatile("s_waitcnt vmcnt(0)" ::: "memory"); } \
    __builtin_amdgcn_s_barrier(); \
    __builtin_amdgcn_sched_barrier(0); \
  }

__global__ __launch_bounds__(512, 2) void gemm_kernel(const ushort* __restrict__ A,
                                                      const ushort* __restrict__ Bt,
                                                      float* __restrict__ C) {
    __shared__ __align__(16) ushort lA[2][2][256 * 32];
    __shared__ __align__(16) ushort lB[2][2][256 * 32];

    const int tid = threadIdx.x;
    const int lane = tid & 63;
    const int wave = tid >> 6;

    // --- round-6 change: n-major XCD mapping ---
    // XCD x (= bid&7) owns n-cols {2x, 2x+1}. First 32 resident blocks of an
    // XCD = all 32 m-tiles x one n-col -> shared 2MB B-panel stays L2-resident.
    int bid = blockIdx.x;                     // nwg = 512
    const int x8 = bid & 7;
    const int j = bid >> 3;                   // 0..63
    const int m0 = (j & 31) * 256;            // 32 m-tiles
    const int n0 = (x8 * 2 + (j >> 5)) * 256; // n-col = 2*xcd + (j>=32)

    const int wr = wave >> 2;                 // 0..1  (M half)
    const int wc = wave & 3;                  // 0..3  (N quarter)
    const int fr = lane & 15;
    const int fq = lane >> 4;                 // 0..3

    const int st_r = tid >> 2;                // 0..127

    // per-thread constant offsets (ushort elems); read swizzle elem-xor ((fr>>1)&3)<<3
    const int sx = ((fr >> 1) & 3) << 3;
    const int aoff = (wr * 128 + fr) * 32 + ((fq << 3) ^ sx);
    const int boff = (wc * 64 + fr) * 32 + ((fq << 3) ^ sx);
    const int doff = tid * 8;                 // linear stage dest
    const int sce = ((tid & 3) << 3) ^ (((st_r >> 1) & 3) << 3);   // inv-swz source
    const ushort* gA0 = A  + (size_t)(m0 + st_r) * DIN + sce;
    const ushort* gA1 = gA0 + (size_t)128 * DIN;
    const ushort* gB0 = Bt + (size_t)(n0 + st_r) * DIN + sce;
    const ushort* gB1 = gB0 + (size_t)128 * DIN;

    f32x4 acc[8][4] = {};

    // prologue: tile0 both halves + tile1.kk0 staged (12 GLL/wave)
    STAGE_A(0, 0, 0)   STAGE_B(0, 0, 0)
    STAGE_A(0, 1, 32)  STAGE_B(0, 1, 32)
    STAGE_A(1, 0, 64)  STAGE_B(1, 0, 64)
    asm volatile("s_waitcnt vmcnt(4)" ::: "memory");   // tile0's 8 loads landed
    __builtin_amdgcn_s_barrier();
    __builtin_amdgcn_sched_barrier(0);

    for (int u = 0; u < NT; u += 2) {
        KTILE(0, 1, (u + 2 < NT), 1, 96, 128)
        KTILE(1, (u + 2 < NT), (u + 3 < NT), (u + 2 < NT), 160, 192)
        gA0 += 128; gA1 += 128; gB0 += 128; gB1 += 128;
    }

    // epilogue: C/D frag layout col=fr, row=fq*4+j
#pragma unroll
    for (int a = 0; a < 8; ++a) {
        int grow = m0 + wr * 128 + (a >> 2) * 64 + (a & 3) * 16 + fq * 4;
#pragma unroll
        for (int n = 0; n < 4; ++n) {
            int gcol = n0 + wc * 64 + n * 16 + fr;
#pragma unroll
            for (int j2 = 0; j2 < 4; ++j2)
                C[(size_t)(grow + j2) * DOUT + gcol] = acc[a][n][j2];
        }
    }
}

extern "C" void kernel_launch(void* const* d_in, const int* in_sizes, int n_in,
                              void* d_out, int out_size, void* d_ws, size_t ws_size,
                              hipStream_t stream) {
    const float* x = (const float*)d_in[0];
    const float* base = (const float*)d_in[1];
    const float* coeff = (const float*)d_in[2];
    const int* mask = (const int*)d_in[3];
    float* out = (float*)d_out;

    const int M = in_sizes[0] / DIN;           // 8192
    ushort* xb = (ushort*)d_ws;                // M*DIN bf16  (64 MB)
    ushort* wt = xb + (size_t)M * DIN;         // DOUT*DIN bf16 (32 MB)

    long n8 = (long)M * DIN / 8;
    cvt_x_kernel<<<(int)((n8 + 255) / 256), 256, 0, stream>>>(x, xb, n8);
    make_wt_kernel<<<(DIN / 64) * (DOUT / 64), 256, 0, stream>>>(base, mask, coeff, wt);

    const int nwg = (M / 256) * (DOUT / 256);  // 512
    gemm_kernel<<<nwg, 512, 0, stream>>>(xb, wt, out);
}

// Round 7
// 325.773 us; speedup vs baseline: 1.6683x; 1.0294x over previous
//
#include <hip/hip_runtime.h>
#include <hip/hip_bf16.h>
#include <stdint.h>

#define DIN 4096
#define DOUT 4096
#define BK 64
#define NT (DIN / BK)   // 64 K-tiles

typedef __attribute__((ext_vector_type(8))) short short8;
typedef __attribute__((ext_vector_type(8))) unsigned short ushort8;
typedef __attribute__((ext_vector_type(4))) float f32x4;

__device__ inline unsigned short f2bf(float f) {
    union { float f; unsigned u; } v; v.f = f;
    unsigned r = v.u + 0x7fffu + ((v.u >> 16) & 1u);   // RNE
    return (unsigned short)(r >> 16);
}

// ---- prep 1: x (f32) -> bf16, 8 elems/thread --------------------------------
__global__ void cvt_x_kernel(const float* __restrict__ x, ushort* __restrict__ xb, long n8) {
    long i = (long)blockIdx.x * blockDim.x + threadIdx.x;
    if (i >= n8) return;
    const float4* p = (const float4*)(x + i * 8);
    float4 v0 = p[0], v1 = p[1];
    ushort8 o;
    o[0] = f2bf(v0.x); o[1] = f2bf(v0.y); o[2] = f2bf(v0.z); o[3] = f2bf(v0.w);
    o[4] = f2bf(v1.x); o[5] = f2bf(v1.y); o[6] = f2bf(v1.z); o[7] = f2bf(v1.w);
    *(ushort8*)(xb + i * 8) = o;
}

// ---- prep 2: Wt[e][d] = bf16(base[d][e] + c*mask[d][e])  (64x64 LDS transpose)
__global__ void make_wt_kernel(const float* __restrict__ base, const int* __restrict__ mask,
                               const float* __restrict__ coeff, ushort* __restrict__ wt) {
    __shared__ float tile[64][65];
    const float c = coeff[0];
    const int t = threadIdx.x;                 // 256 threads
    const int bd = blockIdx.x >> 6;            // d-tile
    const int be = blockIdx.x & 63;            // e-tile
    const int d0 = bd * 64, e0 = be * 64;
#pragma unroll
    for (int i = 0; i < 4; ++i) {
        int idx = i * 256 + t;                 // 0..1023 float4-index
        int r = idx >> 4;                      // d-row 0..63
        int c4 = (idx & 15) << 2;              // e-col
        const float4 bv = *(const float4*)(base + (size_t)(d0 + r) * DOUT + e0 + c4);
        const int4  mv = *(const int4*)(mask + (size_t)(d0 + r) * DOUT + e0 + c4);
        tile[r][c4 + 0] = bv.x + c * (float)mv.x;
        tile[r][c4 + 1] = bv.y + c * (float)mv.y;
        tile[r][c4 + 2] = bv.z + c * (float)mv.z;
        tile[r][c4 + 3] = bv.w + c * (float)mv.w;
    }
    __syncthreads();
#pragma unroll
    for (int i = 0; i < 8; ++i) {
        int idx = i * 256 + t;                 // 0..2047 pair index
        int r = idx >> 5;                      // e-row 0..63
        int p = (idx & 31) << 1;               // d-col pair
        ushort2 o;
        o.x = f2bf(tile[p][r]);
        o.y = f2bf(tile[p + 1][r]);
        *(ushort2*)(wt + (size_t)(e0 + r) * DIN + d0 + p) = o;
    }
}

// ---- GEMM: 256x256 tile, BK=64, 8-phase schedule (T2+T3+T4+T5) --------------
// Round-7 change vs verified round 4: DEEPENED vmcnt protocol only.
//   - boundary wait vmcnt(4) -> vmcnt(6)
//   - new mid-tile vmcnt(6) at phase-2 start (covers kk1-B before ph3 reads)
//   - prologue vmcnt(4) -> vmcnt(6)
// Steady-state FIFO audit (per wave, 2 GLL per stage):
//   entering tile: 6 outstanding [B1->kk1B(next), A0,B0->kk0(next)]
//   ph1 +A1(2)=8 | ph2: WAITV(6) drains B1 (4 phases old) then +B1'(2)=8
//   ph3 +A0'(2)=10 | ph4 +B0'(2)=12 | boundary WAITV(6) drains
//   [kk0(next,4) + A1(2)] -> leaves [B1',A0',B0']=6. Every wait targets
//   loads >=3 phases (~1800 cyc) old -> no latency stall.

#define MFMA(d, va, vb) d = __builtin_amdgcn_mfma_f32_16x16x32_bf16(va, vb, d, 0, 0, 0)

#define GLL(P, L) \
    __builtin_amdgcn_global_load_lds( \
        (const __attribute__((address_space(1))) void*)(P), \
        (__attribute__((address_space(3))) void*)(L), 16, 0, 0)

#define RDA(BUF,KK,OH,MM) (*(const short8*)&lA[BUF][KK][aoff + (OH)*2048 + (MM)*512])
#define RDB(BUF,KK,NN)    (*(const short8*)&lB[BUF][KK][boff + (NN)*512])

#define STAGE_A(BUF,KK,OFE) { GLL(gA0 + (OFE), &lA[BUF][KK][doff]); \
                              GLL(gA1 + (OFE), &lA[BUF][KK][doff + 4096]); }
#define STAGE_B(BUF,KK,OFE) { GLL(gB0 + (OFE), &lB[BUF][KK][doff]); \
                              GLL(gB1 + (OFE), &lB[BUF][KK][doff + 4096]); }

#define WAITV(N)  asm volatile("s_waitcnt vmcnt(" #N ")" ::: "memory")

#define PHASE_CORE(AOFF) \
    __builtin_amdgcn_s_barrier(); \
    asm volatile("s_waitcnt lgkmcnt(0)" ::: "memory"); \
    __builtin_amdgcn_sched_barrier(0); \
    __builtin_amdgcn_s_setprio(1); \
    MFMA(acc[AOFF+0][0],a0,b0); MFMA(acc[AOFF+0][1],a0,b1); MFMA(acc[AOFF+0][2],a0,b2); MFMA(acc[AOFF+0][3],a0,b3); \
    MFMA(acc[AOFF+1][0],a1,b0); MFMA(acc[AOFF+1][1],a1,b1); MFMA(acc[AOFF+1][2],a1,b2); MFMA(acc[AOFF+1][3],a1,b3); \
    MFMA(acc[AOFF+2][0],a2,b0); MFMA(acc[AOFF+2][1],a2,b1); MFMA(acc[AOFF+2][2],a2,b2); MFMA(acc[AOFF+2][3],a2,b3); \
    MFMA(acc[AOFF+3][0],a3,b0); MFMA(acc[AOFF+3][1],a3,b1); MFMA(acc[AOFF+3][2],a3,b2); MFMA(acc[AOFF+3][3],a3,b3); \
    __builtin_amdgcn_s_setprio(0);

// K-tile: 4 phases; stage schedule (verified round 2/4):
//  ph1: stage A.kk1(U+1)->other buf   ph2: stage B.kk1(U+1)
//  ph3: stage A.kk0(U+2)->this buf    ph4: stage B.kk0(U+2)
#define KTILE(BUF, G1, G2, NEXT, OFE1, OFE2) \
  { \
    short8 a0,a1,a2,a3,b0,b1,b2,b3; \
    a0=RDA(BUF,0,0,0); a1=RDA(BUF,0,0,1); a2=RDA(BUF,0,0,2); a3=RDA(BUF,0,0,3); \
    b0=RDB(BUF,0,0); b1=RDB(BUF,0,1); b2=RDB(BUF,0,2); b3=RDB(BUF,0,3); \
    if (G1) STAGE_A(1-(BUF), 1, OFE1) \
    PHASE_CORE(0) \
    __builtin_amdgcn_s_barrier(); \
    WAITV(6); \
    a0=RDA(BUF,0,1,0); a1=RDA(BUF,0,1,1); a2=RDA(BUF,0,1,2); a3=RDA(BUF,0,1,3); \
    if (G1) STAGE_B(1-(BUF), 1, OFE1) \
    PHASE_CORE(4) \
    __builtin_amdgcn_s_barrier(); \
    a0=RDA(BUF,1,0,0); a1=RDA(BUF,1,0,1); a2=RDA(BUF,1,0,2); a3=RDA(BUF,1,0,3); \
    b0=RDB(BUF,1,0); b1=RDB(BUF,1,1); b2=RDB(BUF,1,2); b3=RDB(BUF,1,3); \
    if (G2) STAGE_A(BUF, 0, OFE2) \
    PHASE_CORE(0) \
    __builtin_amdgcn_s_barrier(); \
    a0=RDA(BUF,1,1,0); a1=RDA(BUF,1,1,1); a2=RDA(BUF,1,1,2); a3=RDA(BUF,1,1,3); \
    if (G2) STAGE_B(BUF, 0, OFE2) \
    PHASE_CORE(4) \
    if (G2)        { WAITV(6); } \
    else if (NEXT) { WAITV(0); } \
    __builtin_amdgcn_s_barrier(); \
    __builtin_amdgcn_sched_barrier(0); \
  }

__global__ __launch_bounds__(512, 2) void gemm_kernel(const ushort* __restrict__ A,
                                                      const ushort* __restrict__ Bt,
                                                      float* __restrict__ C) {
    __shared__ __align__(16) ushort lA[2][2][256 * 32];
    __shared__ __align__(16) ushort lB[2][2][256 * 32];

    const int tid = threadIdx.x;
    const int lane = tid & 63;
    const int wave = tid >> 6;

    const int nbn = DOUT / 256;               // 16
    const int nwg = gridDim.x;                // 512 (multiple of 8)
    int bid = blockIdx.x;
    int cpx = nwg >> 3;
    int s = (bid & 7) * cpx + (bid >> 3);     // XCD-contiguous chunks
    const int m0 = (s / nbn) * 256;
    const int n0 = (s % nbn) * 256;

    const int wr = wave >> 2;                 // 0..1  (M half)
    const int wc = wave & 3;                  // 0..3  (N quarter)
    const int fr = lane & 15;
    const int fq = lane >> 4;                 // 0..3

    const int st_r = tid >> 2;                // 0..127

    // per-thread constant offsets (ushort elems); read swizzle elem-xor ((fr>>1)&3)<<3
    const int sx = ((fr >> 1) & 3) << 3;
    const int aoff = (wr * 128 + fr) * 32 + ((fq << 3) ^ sx);
    const int boff = (wc * 64 + fr) * 32 + ((fq << 3) ^ sx);
    const int doff = tid * 8;                 // linear stage dest
    const int sce = ((tid & 3) << 3) ^ (((st_r >> 1) & 3) << 3);   // inv-swz source
    const ushort* gA0 = A  + (size_t)(m0 + st_r) * DIN + sce;
    const ushort* gA1 = gA0 + (size_t)128 * DIN;
    const ushort* gB0 = Bt + (size_t)(n0 + st_r) * DIN + sce;
    const ushort* gB1 = gB0 + (size_t)128 * DIN;

    f32x4 acc[8][4] = {};

    // prologue: tile0 both halves + tile1.kk0 staged (12 GLL/wave)
    // WAITV(6) drains [A00,B00,A01] -> leaves [B01, A10,B10] = steady pattern
    STAGE_A(0, 0, 0)   STAGE_B(0, 0, 0)
    STAGE_A(0, 1, 32)  STAGE_B(0, 1, 32)
    STAGE_A(1, 0, 64)  STAGE_B(1, 0, 64)
    WAITV(6);
    __builtin_amdgcn_s_barrier();
    __builtin_amdgcn_sched_barrier(0);

    for (int u = 0; u < NT; u += 2) {
        KTILE(0, 1, (u + 2 < NT), 1, 96, 128)
        KTILE(1, (u + 2 < NT), (u + 3 < NT), (u + 2 < NT), 160, 192)
        gA0 += 128; gA1 += 128; gB0 += 128; gB1 += 128;
    }

    // epilogue: C/D frag layout col=fr, row=fq*4+j
#pragma unroll
    for (int a = 0; a < 8; ++a) {
        int grow = m0 + wr * 128 + (a >> 2) * 64 + (a & 3) * 16 + fq * 4;
#pragma unroll
        for (int n = 0; n < 4; ++n) {
            int gcol = n0 + wc * 64 + n * 16 + fr;
#pragma unroll
            for (int j = 0; j < 4; ++j)
                C[(size_t)(grow + j) * DOUT + gcol] = acc[a][n][j];
        }
    }
}

extern "C" void kernel_launch(void* const* d_in, const int* in_sizes, int n_in,
                              void* d_out, int out_size, void* d_ws, size_t ws_size,
                              hipStream_t stream) {
    const float* x = (const float*)d_in[0];
    const float* base = (const float*)d_in[1];
    const float* coeff = (const float*)d_in[2];
    const int* mask = (const int*)d_in[3];
    float* out = (float*)d_out;

    const int M = in_sizes[0] / DIN;           // 8192
    ushort* xb = (ushort*)d_ws;                // M*DIN bf16  (64 MB)
    ushort* wt = xb + (size_t)M * DIN;         // DOUT*DIN bf16 (32 MB)

    long n8 = (long)M * DIN / 8;
    cvt_x_kernel<<<(int)((n8 + 255) / 256), 256, 0, stream>>>(x, xb, n8);
    make_wt_kernel<<<(DIN / 64) * (DOUT / 64), 256, 0, stream>>>(base, mask, coeff, wt);

    const int nwg = (M / 256) * (DOUT / 256);  // 512
    gemm_kernel<<<nwg, 512, 0, stream>>>(xb, wt, out);
}

// Round 8
// 322.175 us; speedup vs baseline: 1.6869x; 1.0112x over previous
//
#include <hip/hip_runtime.h>
#include <hip/hip_bf16.h>
#include <stdint.h>

#define DIN 4096
#define DOUT 4096
#define BK 64
#define NT (DIN / BK)   // 64 K-tiles

typedef __attribute__((ext_vector_type(8))) short short8;
typedef __attribute__((ext_vector_type(8))) unsigned short ushort8;
typedef __attribute__((ext_vector_type(4))) float f32x4;

__device__ inline unsigned short f2bf(float f) {
    union { float f; unsigned u; } v; v.f = f;
    unsigned r = v.u + 0x7fffu + ((v.u >> 16) & 1u);   // RNE
    return (unsigned short)(r >> 16);
}

// ---- prep 1: x (f32) -> bf16, 8 elems/thread --------------------------------
__global__ void cvt_x_kernel(const float* __restrict__ x, ushort* __restrict__ xb, long n8) {
    long i = (long)blockIdx.x * blockDim.x + threadIdx.x;
    if (i >= n8) return;
    const float4* p = (const float4*)(x + i * 8);
    float4 v0 = p[0], v1 = p[1];
    ushort8 o;
    o[0] = f2bf(v0.x); o[1] = f2bf(v0.y); o[2] = f2bf(v0.z); o[3] = f2bf(v0.w);
    o[4] = f2bf(v1.x); o[5] = f2bf(v1.y); o[6] = f2bf(v1.z); o[7] = f2bf(v1.w);
    *(ushort8*)(xb + i * 8) = o;
}

// ---- prep 2: Wt[e][d] = bf16(base[d][e] + c*mask[d][e])  (64x64 LDS transpose)
__global__ void make_wt_kernel(const float* __restrict__ base, const int* __restrict__ mask,
                               const float* __restrict__ coeff, ushort* __restrict__ wt) {
    __shared__ float tile[64][65];
    const float c = coeff[0];
    const int t = threadIdx.x;                 // 256 threads
    const int bd = blockIdx.x >> 6;            // d-tile
    const int be = blockIdx.x & 63;            // e-tile
    const int d0 = bd * 64, e0 = be * 64;
#pragma unroll
    for (int i = 0; i < 4; ++i) {
        int idx = i * 256 + t;                 // 0..1023 float4-index
        int r = idx >> 4;                      // d-row 0..63
        int c4 = (idx & 15) << 2;              // e-col
        const float4 bv = *(const float4*)(base + (size_t)(d0 + r) * DOUT + e0 + c4);
        const int4  mv = *(const int4*)(mask + (size_t)(d0 + r) * DOUT + e0 + c4);
        tile[r][c4 + 0] = bv.x + c * (float)mv.x;
        tile[r][c4 + 1] = bv.y + c * (float)mv.y;
        tile[r][c4 + 2] = bv.z + c * (float)mv.z;
        tile[r][c4 + 3] = bv.w + c * (float)mv.w;
    }
    __syncthreads();
#pragma unroll
    for (int i = 0; i < 8; ++i) {
        int idx = i * 256 + t;                 // 0..2047 pair index
        int r = idx >> 5;                      // e-row 0..63
        int p = (idx & 31) << 1;               // d-col pair
        ushort2 o;
        o.x = f2bf(tile[p][r]);
        o.y = f2bf(tile[p + 1][r]);
        *(ushort2*)(wt + (size_t)(e0 + r) * DIN + d0 + p) = o;
    }
}

// ---- GEMM: 256x256 tile, BK=64, 8-phase schedule ----------------------------
// Round-8 change vs round 7 (passed, 286us): PHASE_CORE drops the explicit
// `s_waitcnt lgkmcnt(0)` + sched_barrier(0). The compiler's own fine-grained
// register-dependency lgkm waits (lgkmcnt(4/3/1/0) style) now interleave the
// LDS drain with the MFMA cluster instead of serializing drain-then-compute.
// Cross-wave protocol (raw barriers + counted vmcnt) unchanged — lgkmcnt only
// tracks the wave's own DS ops, so the explicit full drain was never needed
// for correctness.

#define MFMA(d, va, vb) d = __builtin_amdgcn_mfma_f32_16x16x32_bf16(va, vb, d, 0, 0, 0)

#define GLL(P, L) \
    __builtin_amdgcn_global_load_lds( \
        (const __attribute__((address_space(1))) void*)(P), \
        (__attribute__((address_space(3))) void*)(L), 16, 0, 0)

#define RDA(BUF,KK,OH,MM) (*(const short8*)&lA[BUF][KK][aoff + (OH)*2048 + (MM)*512])
#define RDB(BUF,KK,NN)    (*(const short8*)&lB[BUF][KK][boff + (NN)*512])

#define STAGE_A(BUF,KK,OFE) { GLL(gA0 + (OFE), &lA[BUF][KK][doff]); \
                              GLL(gA1 + (OFE), &lA[BUF][KK][doff + 4096]); }
#define STAGE_B(BUF,KK,OFE) { GLL(gB0 + (OFE), &lB[BUF][KK][doff]); \
                              GLL(gB1 + (OFE), &lB[BUF][KK][doff + 4096]); }

#define WAITV(N)  asm volatile("s_waitcnt vmcnt(" #N ")" ::: "memory")

#define PHASE_CORE(AOFF) \
    __builtin_amdgcn_s_barrier(); \
    __builtin_amdgcn_s_setprio(1); \
    MFMA(acc[AOFF+0][0],a0,b0); MFMA(acc[AOFF+0][1],a0,b1); MFMA(acc[AOFF+0][2],a0,b2); MFMA(acc[AOFF+0][3],a0,b3); \
    MFMA(acc[AOFF+1][0],a1,b0); MFMA(acc[AOFF+1][1],a1,b1); MFMA(acc[AOFF+1][2],a1,b2); MFMA(acc[AOFF+1][3],a1,b3); \
    MFMA(acc[AOFF+2][0],a2,b0); MFMA(acc[AOFF+2][1],a2,b1); MFMA(acc[AOFF+2][2],a2,b2); MFMA(acc[AOFF+2][3],a2,b3); \
    MFMA(acc[AOFF+3][0],a3,b0); MFMA(acc[AOFF+3][1],a3,b1); MFMA(acc[AOFF+3][2],a3,b2); MFMA(acc[AOFF+3][3],a3,b3); \
    __builtin_amdgcn_s_setprio(0);

// K-tile: 4 phases; stage schedule (verified rounds 2/4/7):
//  ph1: stage A.kk1(U+1)->other buf   ph2: stage B.kk1(U+1)
//  ph3: stage A.kk0(U+2)->this buf    ph4: stage B.kk0(U+2)
// vmcnt protocol as round 7 (passed): mid-tile WAITV(6) at ph2, boundary
// WAITV(6) steady / WAITV(0) tail. Every wait targets loads >=3 phases old.
#define KTILE(BUF, G1, G2, NEXT, OFE1, OFE2) \
  { \
    short8 a0,a1,a2,a3,b0,b1,b2,b3; \
    a0=RDA(BUF,0,0,0); a1=RDA(BUF,0,0,1); a2=RDA(BUF,0,0,2); a3=RDA(BUF,0,0,3); \
    b0=RDB(BUF,0,0); b1=RDB(BUF,0,1); b2=RDB(BUF,0,2); b3=RDB(BUF,0,3); \
    if (G1) STAGE_A(1-(BUF), 1, OFE1) \
    PHASE_CORE(0) \
    __builtin_amdgcn_s_barrier(); \
    WAITV(6); \
    a0=RDA(BUF,0,1,0); a1=RDA(BUF,0,1,1); a2=RDA(BUF,0,1,2); a3=RDA(BUF,0,1,3); \
    if (G1) STAGE_B(1-(BUF), 1, OFE1) \
    PHASE_CORE(4) \
    __builtin_amdgcn_s_barrier(); \
    a0=RDA(BUF,1,0,0); a1=RDA(BUF,1,0,1); a2=RDA(BUF,1,0,2); a3=RDA(BUF,1,0,3); \
    b0=RDB(BUF,1,0); b1=RDB(BUF,1,1); b2=RDB(BUF,1,2); b3=RDB(BUF,1,3); \
    if (G2) STAGE_A(BUF, 0, OFE2) \
    PHASE_CORE(0) \
    __builtin_amdgcn_s_barrier(); \
    a0=RDA(BUF,1,1,0); a1=RDA(BUF,1,1,1); a2=RDA(BUF,1,1,2); a3=RDA(BUF,1,1,3); \
    if (G2) STAGE_B(BUF, 0, OFE2) \
    PHASE_CORE(4) \
    if (G2)        { WAITV(6); } \
    else if (NEXT) { WAITV(0); } \
    __builtin_amdgcn_s_barrier(); \
    __builtin_amdgcn_sched_barrier(0); \
  }

__global__ __launch_bounds__(512, 2) void gemm_kernel(const ushort* __restrict__ A,
                                                      const ushort* __restrict__ Bt,
                                                      float* __restrict__ C) {
    __shared__ __align__(16) ushort lA[2][2][256 * 32];
    __shared__ __align__(16) ushort lB[2][2][256 * 32];

    const int tid = threadIdx.x;
    const int lane = tid & 63;
    const int wave = tid >> 6;

    const int nbn = DOUT / 256;               // 16
    const int nwg = gridDim.x;                // 512 (multiple of 8)
    int bid = blockIdx.x;
    int cpx = nwg >> 3;
    int s = (bid & 7) * cpx + (bid >> 3);     // XCD-contiguous chunks
    const int m0 = (s / nbn) * 256;
    const int n0 = (s % nbn) * 256;

    const int wr = wave >> 2;                 // 0..1  (M half)
    const int wc = wave & 3;                  // 0..3  (N quarter)
    const int fr = lane & 15;
    const int fq = lane >> 4;                 // 0..3

    const int st_r = tid >> 2;                // 0..127

    // per-thread constant offsets (ushort elems); read swizzle elem-xor ((fr>>1)&3)<<3
    const int sx = ((fr >> 1) & 3) << 3;
    const int aoff = (wr * 128 + fr) * 32 + ((fq << 3) ^ sx);
    const int boff = (wc * 64 + fr) * 32 + ((fq << 3) ^ sx);
    const int doff = tid * 8;                 // linear stage dest
    const int sce = ((tid & 3) << 3) ^ (((st_r >> 1) & 3) << 3);   // inv-swz source
    const ushort* gA0 = A  + (size_t)(m0 + st_r) * DIN + sce;
    const ushort* gA1 = gA0 + (size_t)128 * DIN;
    const ushort* gB0 = Bt + (size_t)(n0 + st_r) * DIN + sce;
    const ushort* gB1 = gB0 + (size_t)128 * DIN;

    f32x4 acc[8][4] = {};

    // prologue: tile0 both halves + tile1.kk0 staged (12 GLL/wave)
    STAGE_A(0, 0, 0)   STAGE_B(0, 0, 0)
    STAGE_A(0, 1, 32)  STAGE_B(0, 1, 32)
    STAGE_A(1, 0, 64)  STAGE_B(1, 0, 64)
    WAITV(6);
    __builtin_amdgcn_s_barrier();
    __builtin_amdgcn_sched_barrier(0);

    for (int u = 0; u < NT; u += 2) {
        KTILE(0, 1, (u + 2 < NT), 1, 96, 128)
        KTILE(1, (u + 2 < NT), (u + 3 < NT), (u + 2 < NT), 160, 192)
        gA0 += 128; gA1 += 128; gB0 += 128; gB1 += 128;
    }

    // epilogue: C/D frag layout col=fr, row=fq*4+j
#pragma unroll
    for (int a = 0; a < 8; ++a) {
        int grow = m0 + wr * 128 + (a >> 2) * 64 + (a & 3) * 16 + fq * 4;
#pragma unroll
        for (int n = 0; n < 4; ++n) {
            int gcol = n0 + wc * 64 + n * 16 + fr;
#pragma unroll
            for (int j = 0; j < 4; ++j)
                C[(size_t)(grow + j) * DOUT + gcol] = acc[a][n][j];
        }
    }
}

extern "C" void kernel_launch(void* const* d_in, const int* in_sizes, int n_in,
                              void* d_out, int out_size, void* d_ws, size_t ws_size,
                              hipStream_t stream) {
    const float* x = (const float*)d_in[0];
    const float* base = (const float*)d_in[1];
    const float* coeff = (const float*)d_in[2];
    const int* mask = (const int*)d_in[3];
    float* out = (float*)d_out;

    const int M = in_sizes[0] / DIN;           // 8192
    ushort* xb = (ushort*)d_ws;                // M*DIN bf16  (64 MB)
    ushort* wt = xb + (size_t)M * DIN;         // DOUT*DIN bf16 (32 MB)

    long n8 = (long)M * DIN / 8;
    cvt_x_kernel<<<(int)((n8 + 255) / 256), 256, 0, stream>>>(x, xb, n8);
    make_wt_kernel<<<(DIN / 64) * (DOUT / 64), 256, 0, stream>>>(base, mask, coeff, wt);

    const int nwg = (M / 256) * (DOUT / 256);  // 512
    gemm_kernel<<<nwg, 512, 0, stream>>>(xb, wt, out);
}

// Round 9
// 314.817 us; speedup vs baseline: 1.7263x; 1.0234x over previous
//
#include <hip/hip_runtime.h>
#include <hip/hip_bf16.h>
#include <stdint.h>

#define DIN 4096
#define DOUT 4096
#define BK 64
#define NT (DIN / BK)   // 64 K-tiles

typedef __attribute__((ext_vector_type(8))) short short8;
typedef __attribute__((ext_vector_type(8))) unsigned short ushort8;
typedef __attribute__((ext_vector_type(4))) float f32x4;

__device__ inline unsigned short f2bf(float f) {
    union { float f; unsigned u; } v; v.f = f;
    unsigned r = v.u + 0x7fffu + ((v.u >> 16) & 1u);   // RNE
    return (unsigned short)(r >> 16);
}

// ---- prep 1: x (f32) -> bf16, 8 elems/thread --------------------------------
__global__ void cvt_x_kernel(const float* __restrict__ x, ushort* __restrict__ xb, long n8) {
    long i = (long)blockIdx.x * blockDim.x + threadIdx.x;
    if (i >= n8) return;
    const float4* p = (const float4*)(x + i * 8);
    float4 v0 = p[0], v1 = p[1];
    ushort8 o;
    o[0] = f2bf(v0.x); o[1] = f2bf(v0.y); o[2] = f2bf(v0.z); o[3] = f2bf(v0.w);
    o[4] = f2bf(v1.x); o[5] = f2bf(v1.y); o[6] = f2bf(v1.z); o[7] = f2bf(v1.w);
    *(ushort8*)(xb + i * 8) = o;
}

// ---- prep 2: Wt[e][d] = bf16(base[d][e] + c*mask[d][e])  (64x64 LDS transpose)
__global__ void make_wt_kernel(const float* __restrict__ base, const int* __restrict__ mask,
                               const float* __restrict__ coeff, ushort* __restrict__ wt) {
    __shared__ float tile[64][65];
    const float c = coeff[0];
    const int t = threadIdx.x;                 // 256 threads
    const int bd = blockIdx.x >> 6;            // d-tile
    const int be = blockIdx.x & 63;            // e-tile
    const int d0 = bd * 64, e0 = be * 64;
#pragma unroll
    for (int i = 0; i < 4; ++i) {
        int idx = i * 256 + t;                 // 0..1023 float4-index
        int r = idx >> 4;                      // d-row 0..63
        int c4 = (idx & 15) << 2;              // e-col
        const float4 bv = *(const float4*)(base + (size_t)(d0 + r) * DOUT + e0 + c4);
        const int4  mv = *(const int4*)(mask + (size_t)(d0 + r) * DOUT + e0 + c4);
        tile[r][c4 + 0] = bv.x + c * (float)mv.x;
        tile[r][c4 + 1] = bv.y + c * (float)mv.y;
        tile[r][c4 + 2] = bv.z + c * (float)mv.z;
        tile[r][c4 + 3] = bv.w + c * (float)mv.w;
    }
    __syncthreads();
#pragma unroll
    for (int i = 0; i < 8; ++i) {
        int idx = i * 256 + t;                 // 0..2047 pair index
        int r = idx >> 5;                      // e-row 0..63
        int p = (idx & 31) << 1;               // d-col pair
        ushort2 o;
        o.x = f2bf(tile[p][r]);
        o.y = f2bf(tile[p + 1][r]);
        *(ushort2*)(wt + (size_t)(e0 + r) * DIN + d0 + p) = o;
    }
}

// ---- GEMM: 256x256 tile, BK=64, 8-phase, de-lockstepped ---------------------
// Round-9 change vs round 8: the POST-MFMA barriers are removed (8 -> 5
// barriers per K-tile). Correctness: every STAGE issue remains protected by a
// PRE-MFMA barrier that transitively guarantees all prior reads of its target
// region completed (ph3's stage after BAR(ph3) > all ph2 MFMAs > their lgkm
// waits > all kk0-A reads; ph4/kk0-B analogous; ph1/ph2 stage the other
// buffer whose readers finished before the boundary barrier). vmcnt protocol
// identical to rounds 7/8. Waves may now de-phase by one region: a wave
// finishing MFMA (setprio 0) issues next reads/stages while the other wave
// on its SIMD is still MFMA-ing (setprio 1) -> cross-wave LDS/MFMA overlap.

#define MFMA(d, va, vb) d = __builtin_amdgcn_mfma_f32_16x16x32_bf16(va, vb, d, 0, 0, 0)

#define GLL(P, L) \
    __builtin_amdgcn_global_load_lds( \
        (const __attribute__((address_space(1))) void*)(P), \
        (__attribute__((address_space(3))) void*)(L), 16, 0, 0)

#define RDA(BUF,KK,OH,MM) (*(const short8*)&lA[BUF][KK][aoff + (OH)*2048 + (MM)*512])
#define RDB(BUF,KK,NN)    (*(const short8*)&lB[BUF][KK][boff + (NN)*512])

#define STAGE_A(BUF,KK,OFE) { GLL(gA0 + (OFE), &lA[BUF][KK][doff]); \
                              GLL(gA1 + (OFE), &lA[BUF][KK][doff + 4096]); }
#define STAGE_B(BUF,KK,OFE) { GLL(gB0 + (OFE), &lB[BUF][KK][doff]); \
                              GLL(gB1 + (OFE), &lB[BUF][KK][doff + 4096]); }

#define WAITV(N)  asm volatile("s_waitcnt vmcnt(" #N ")" ::: "memory")

#define PHASE_CORE(AOFF) \
    __builtin_amdgcn_s_barrier(); \
    __builtin_amdgcn_s_setprio(1); \
    MFMA(acc[AOFF+0][0],a0,b0); MFMA(acc[AOFF+0][1],a0,b1); MFMA(acc[AOFF+0][2],a0,b2); MFMA(acc[AOFF+0][3],a0,b3); \
    MFMA(acc[AOFF+1][0],a1,b0); MFMA(acc[AOFF+1][1],a1,b1); MFMA(acc[AOFF+1][2],a1,b2); MFMA(acc[AOFF+1][3],a1,b3); \
    MFMA(acc[AOFF+2][0],a2,b0); MFMA(acc[AOFF+2][1],a2,b1); MFMA(acc[AOFF+2][2],a2,b2); MFMA(acc[AOFF+2][3],a2,b3); \
    MFMA(acc[AOFF+3][0],a3,b0); MFMA(acc[AOFF+3][1],a3,b1); MFMA(acc[AOFF+3][2],a3,b2); MFMA(acc[AOFF+3][3],a3,b3); \
    __builtin_amdgcn_s_setprio(0);

// K-tile: 4 phases; stage schedule (verified rounds 2/4/7/8):
//  ph1: stage A.kk1(U+1)->other buf   ph2: stage B.kk1(U+1)
//  ph3: stage A.kk0(U+2)->this buf    ph4: stage B.kk0(U+2)
// vmcnt: mid-tile WAITV(6) before ph2 reads, boundary WAITV(6)/WAITV(0).
#define KTILE(BUF, G1, G2, NEXT, OFE1, OFE2) \
  { \
    short8 a0,a1,a2,a3,b0,b1,b2,b3; \
    a0=RDA(BUF,0,0,0); a1=RDA(BUF,0,0,1); a2=RDA(BUF,0,0,2); a3=RDA(BUF,0,0,3); \
    b0=RDB(BUF,0,0); b1=RDB(BUF,0,1); b2=RDB(BUF,0,2); b3=RDB(BUF,0,3); \
    if (G1) STAGE_A(1-(BUF), 1, OFE1) \
    PHASE_CORE(0) \
    WAITV(6); \
    a0=RDA(BUF,0,1,0); a1=RDA(BUF,0,1,1); a2=RDA(BUF,0,1,2); a3=RDA(BUF,0,1,3); \
    if (G1) STAGE_B(1-(BUF), 1, OFE1) \
    PHASE_CORE(4) \
    a0=RDA(BUF,1,0,0); a1=RDA(BUF,1,0,1); a2=RDA(BUF,1,0,2); a3=RDA(BUF,1,0,3); \
    b0=RDB(BUF,1,0); b1=RDB(BUF,1,1); b2=RDB(BUF,1,2); b3=RDB(BUF,1,3); \
    if (G2) STAGE_A(BUF, 0, OFE2) \
    PHASE_CORE(0) \
    a0=RDA(BUF,1,1,0); a1=RDA(BUF,1,1,1); a2=RDA(BUF,1,1,2); a3=RDA(BUF,1,1,3); \
    if (G2) STAGE_B(BUF, 0, OFE2) \
    PHASE_CORE(4) \
    if (G2)        { WAITV(6); } \
    else if (NEXT) { WAITV(0); } \
    __builtin_amdgcn_s_barrier(); \
    __builtin_amdgcn_sched_barrier(0); \
  }

__global__ __launch_bounds__(512, 2) void gemm_kernel(const ushort* __restrict__ A,
                                                      const ushort* __restrict__ Bt,
                                                      float* __restrict__ C) {
    __shared__ __align__(16) ushort lA[2][2][256 * 32];
    __shared__ __align__(16) ushort lB[2][2][256 * 32];

    const int tid = threadIdx.x;
    const int lane = tid & 63;
    const int wave = tid >> 6;

    const int nbn = DOUT / 256;               // 16
    const int nwg = gridDim.x;                // 512 (multiple of 8)
    int bid = blockIdx.x;
    int cpx = nwg >> 3;
    int s = (bid & 7) * cpx + (bid >> 3);     // XCD-contiguous chunks
    const int m0 = (s / nbn) * 256;
    const int n0 = (s % nbn) * 256;

    const int wr = wave >> 2;                 // 0..1  (M half)
    const int wc = wave & 3;                  // 0..3  (N quarter)
    const int fr = lane & 15;
    const int fq = lane >> 4;                 // 0..3

    const int st_r = tid >> 2;                // 0..127

    // per-thread constant offsets (ushort elems); read swizzle elem-xor ((fr>>1)&3)<<3
    const int sx = ((fr >> 1) & 3) << 3;
    const int aoff = (wr * 128 + fr) * 32 + ((fq << 3) ^ sx);
    const int boff = (wc * 64 + fr) * 32 + ((fq << 3) ^ sx);
    const int doff = tid * 8;                 // linear stage dest
    const int sce = ((tid & 3) << 3) ^ (((st_r >> 1) & 3) << 3);   // inv-swz source
    const ushort* gA0 = A  + (size_t)(m0 + st_r) * DIN + sce;
    const ushort* gA1 = gA0 + (size_t)128 * DIN;
    const ushort* gB0 = Bt + (size_t)(n0 + st_r) * DIN + sce;
    const ushort* gB1 = gB0 + (size_t)128 * DIN;

    f32x4 acc[8][4] = {};

    // prologue: tile0 both halves + tile1.kk0 staged (12 GLL/wave)
    STAGE_A(0, 0, 0)   STAGE_B(0, 0, 0)
    STAGE_A(0, 1, 32)  STAGE_B(0, 1, 32)
    STAGE_A(1, 0, 64)  STAGE_B(1, 0, 64)
    WAITV(6);
    __builtin_amdgcn_s_barrier();
    __builtin_amdgcn_sched_barrier(0);

    for (int u = 0; u < NT; u += 2) {
        KTILE(0, 1, (u + 2 < NT), 1, 96, 128)
        KTILE(1, (u + 2 < NT), (u + 3 < NT), (u + 2 < NT), 160, 192)
        gA0 += 128; gA1 += 128; gB0 += 128; gB1 += 128;
    }

    // epilogue: C/D frag layout col=fr, row=fq*4+j
#pragma unroll
    for (int a = 0; a < 8; ++a) {
        int grow = m0 + wr * 128 + (a >> 2) * 64 + (a & 3) * 16 + fq * 4;
#pragma unroll
        for (int n = 0; n < 4; ++n) {
            int gcol = n0 + wc * 64 + n * 16 + fr;
#pragma unroll
            for (int j = 0; j < 4; ++j)
                C[(size_t)(grow + j) * DOUT + gcol] = acc[a][n][j];
        }
    }
}

extern "C" void kernel_launch(void* const* d_in, const int* in_sizes, int n_in,
                              void* d_out, int out_size, void* d_ws, size_t ws_size,
                              hipStream_t stream) {
    const float* x = (const float*)d_in[0];
    const float* base = (const float*)d_in[1];
    const float* coeff = (const float*)d_in[2];
    const int* mask = (const int*)d_in[3];
    float* out = (float*)d_out;

    const int M = in_sizes[0] / DIN;           // 8192
    ushort* xb = (ushort*)d_ws;                // M*DIN bf16  (64 MB)
    ushort* wt = xb + (size_t)M * DIN;         // DOUT*DIN bf16 (32 MB)

    long n8 = (long)M * DIN / 8;
    cvt_x_kernel<<<(int)((n8 + 255) / 256), 256, 0, stream>>>(x, xb, n8);
    make_wt_kernel<<<(DIN / 64) * (DOUT / 64), 256, 0, stream>>>(base, mask, coeff, wt);

    const int nwg = (M / 256) * (DOUT / 256);  // 512
    gemm_kernel<<<nwg, 512, 0, stream>>>(xb, wt, out);
}